// Round 1
// baseline (1089.212 us; speedup 1.0000x reference)
//
#include <hip/hip_runtime.h>

constexpr int NN = 100000;
constexpr int NE = 800000;

// ---------------------------------------------------------------------------
// count kernel: cnt[dst] += 1  (shared by both layers)
__global__ __launch_bounds__(256)
void count_kernel(const int* __restrict__ dst, float* __restrict__ cnt, int E) {
    for (int i = blockIdx.x * blockDim.x + threadIdx.x; i < E;
         i += gridDim.x * blockDim.x)
        unsafeAtomicAdd(&cnt[dst[i]], 1.0f);
}

__global__ __launch_bounds__(256)
void inv_kernel(const float* __restrict__ cnt, float* __restrict__ invc, int n) {
    int i = blockIdx.x * blockDim.x + threadIdx.x;
    if (i < n) invc[i] = 1.0f / fmaxf(cnt[i], 1.0f);
}

// ---------------------------------------------------------------------------
// GEMM: C[M,128] = act(A[M,K] @ W[K,128] + bias)
// CONCAT: A = [A1 | A2*invc]  (K=256), else A = A1 (K=128)
// LNRELU: relu then layernorm(g,beta) fused epilogue
template<bool CONCAT, bool LNRELU>
__global__ __launch_bounds__(256)
void gemm_kernel(const float* __restrict__ A1, const float* __restrict__ A2,
                 const float* __restrict__ invc,
                 const float* __restrict__ W, const float* __restrict__ bias,
                 const float* __restrict__ g, const float* __restrict__ beta,
                 float* __restrict__ C, int M, int K)
{
    __shared__ float As[32][68];    // A-tile transposed [k][row], padded
    __shared__ float Bs[32][132];   // W-tile [k][col], padded

    const int tid = threadIdx.x;
    const int tx = tid & 15;        // col group: cols tx*8 .. tx*8+7
    const int ty = tid >> 4;        // row group: rows ty*4 .. ty*4+3
    const int brow = blockIdx.x * 64;

    float acc[4][8];
#pragma unroll
    for (int i = 0; i < 4; i++)
#pragma unroll
        for (int j = 0; j < 8; j++) acc[i][j] = 0.0f;

    for (int k0 = 0; k0 < K; k0 += 32) {
        // ---- stage A tile (64 rows x 32 k), transposed into LDS
#pragma unroll
        for (int j = 0; j < 2; j++) {
            int f = tid + j * 256;          // 0..511 float4 slots
            int r = f >> 3;                 // row in tile
            int kc = f & 7;                 // float4 index along k
            int grow = brow + r;
            float4 v = make_float4(0.f, 0.f, 0.f, 0.f);
            if (grow < M) {
                if (!CONCAT || k0 < 128) {
                    v = *reinterpret_cast<const float4*>(
                        &A1[(size_t)grow * 128 + k0 + kc * 4]);
                } else {
                    v = *reinterpret_cast<const float4*>(
                        &A2[(size_t)grow * 128 + (k0 - 128) + kc * 4]);
                    float s = invc[grow];
                    v.x *= s; v.y *= s; v.z *= s; v.w *= s;
                }
            }
            As[kc * 4 + 0][r] = v.x;
            As[kc * 4 + 1][r] = v.y;
            As[kc * 4 + 2][r] = v.z;
            As[kc * 4 + 3][r] = v.w;
        }
        // ---- stage B tile (32 k x 128 cols)
#pragma unroll
        for (int j = 0; j < 4; j++) {
            int f = tid + j * 256;          // 0..1023 float4 slots
            int kk = f >> 5;
            int col = (f & 31) * 4;
            *reinterpret_cast<float4*>(&Bs[kk][col]) =
                *reinterpret_cast<const float4*>(&W[(size_t)(k0 + kk) * 128 + col]);
        }
        __syncthreads();

#pragma unroll
        for (int kk = 0; kk < 32; kk++) {
            float4 a4 = *reinterpret_cast<const float4*>(&As[kk][ty * 4]);
            float4 b0 = *reinterpret_cast<const float4*>(&Bs[kk][tx * 8]);
            float4 b1 = *reinterpret_cast<const float4*>(&Bs[kk][tx * 8 + 4]);
            float a[4] = {a4.x, a4.y, a4.z, a4.w};
            float b[8] = {b0.x, b0.y, b0.z, b0.w, b1.x, b1.y, b1.z, b1.w};
#pragma unroll
            for (int i = 0; i < 4; i++)
#pragma unroll
                for (int j = 0; j < 8; j++)
                    acc[i][j] = fmaf(a[i], b[j], acc[i][j]);
        }
        __syncthreads();
    }

    // ---- epilogue
    float bb[8];
#pragma unroll
    for (int j = 0; j < 8; j++) bb[j] = bias[tx * 8 + j];

    if (LNRELU) {
        float gg[8], be2[8];
#pragma unroll
        for (int j = 0; j < 8; j++) { gg[j] = g[tx * 8 + j]; be2[j] = beta[tx * 8 + j]; }
#pragma unroll
        for (int i = 0; i < 4; i++) {
            float v[8], s = 0.f, s2 = 0.f;
#pragma unroll
            for (int j = 0; j < 8; j++) {
                float t = fmaxf(acc[i][j] + bb[j], 0.0f);
                v[j] = t; s += t; s2 += t * t;
            }
#pragma unroll
            for (int m = 1; m < 16; m <<= 1) {
                s  += __shfl_xor(s, m, 64);
                s2 += __shfl_xor(s2, m, 64);
            }
            float mean = s * (1.0f / 128.0f);
            float var  = s2 * (1.0f / 128.0f) - mean * mean;
            float rstd = rsqrtf(var + 1e-5f);
            int grow = brow + ty * 4 + i;
            if (grow < M) {
                float o[8];
#pragma unroll
                for (int j = 0; j < 8; j++)
                    o[j] = (v[j] - mean) * rstd * gg[j] + be2[j];
                float4* p = reinterpret_cast<float4*>(&C[(size_t)grow * 128 + tx * 8]);
                p[0] = make_float4(o[0], o[1], o[2], o[3]);
                p[1] = make_float4(o[4], o[5], o[6], o[7]);
            }
        }
    } else {
#pragma unroll
        for (int i = 0; i < 4; i++) {
            int grow = brow + ty * 4 + i;
            if (grow < M) {
                float o[8];
#pragma unroll
                for (int j = 0; j < 8; j++) o[j] = acc[i][j] + bb[j];
                float4* p = reinterpret_cast<float4*>(&C[(size_t)grow * 128 + tx * 8]);
                p[0] = make_float4(o[0], o[1], o[2], o[3]);
                p[1] = make_float4(o[4], o[5], o[6], o[7]);
            }
        }
    }
}

// ---------------------------------------------------------------------------
// fused edge-transform + gather + scatter-add
// per edge e: msg = nt[src[e]] + (edge_attr[e] @ We + be); agg[dst[e]] += msg
// one wave per edge; We (16KB) staged in LDS.
__global__ __launch_bounds__(256)
void msg_kernel(const float* __restrict__ edge_attr,
                const float* __restrict__ We, const float* __restrict__ be,
                const float* __restrict__ nt,
                const int* __restrict__ src, const int* __restrict__ dst,
                float* __restrict__ agg, int E)
{
    __shared__ float Ws[32][128];
    __shared__ float bs[128];
    __shared__ float eas[4][32];

    const int tid = threadIdx.x;
#pragma unroll
    for (int j = 0; j < 4; j++) {
        int f = tid + j * 256;
        int kk = f >> 5;
        int col = (f & 31) * 4;
        *reinterpret_cast<float4*>(&Ws[kk][col]) =
            *reinterpret_cast<const float4*>(&We[(size_t)kk * 128 + col]);
    }
    if (tid < 128) bs[tid] = be[tid];
    __syncthreads();

    const int wid = tid >> 6;
    const int lane = tid & 63;
    for (int e = blockIdx.x * 4 + wid; e < E; e += gridDim.x * 4) {
        if (lane < 32) eas[wid][lane] = edge_attr[(size_t)e * 32 + lane];
        // intra-wave LDS dependency: compiler inserts lgkmcnt wait, no barrier
        int s = src[e], d = dst[e];
        float v0 = bs[lane], v1 = bs[lane + 64];
#pragma unroll
        for (int k = 0; k < 32; k++) {
            float ev = eas[wid][k];
            v0 = fmaf(ev, Ws[k][lane], v0);
            v1 = fmaf(ev, Ws[k][lane + 64], v1);
        }
        const float* ntp = &nt[(size_t)s * 128];
        v0 += ntp[lane];
        v1 += ntp[lane + 64];
        unsafeAtomicAdd(&agg[(size_t)d * 128 + lane], v0);
        unsafeAtomicAdd(&agg[(size_t)d * 128 + lane + 64], v1);
    }
}

// ---------------------------------------------------------------------------
extern "C" void kernel_launch(void* const* d_in, const int* in_sizes, int n_in,
                              void* d_out, int out_size, void* d_ws, size_t ws_size,
                              hipStream_t stream)
{
    const float* x    = (const float*)d_in[0];
    const int*   ei   = (const int*)d_in[1];
    const float* ea   = (const float*)d_in[2];
    const float* Wn1  = (const float*)d_in[3];
    const float* bn1  = (const float*)d_in[4];
    const float* We1  = (const float*)d_in[5];
    const float* be1  = (const float*)d_in[6];
    const float* Wu1  = (const float*)d_in[7];
    const float* bu1  = (const float*)d_in[8];
    const float* g1   = (const float*)d_in[9];
    const float* beta1= (const float*)d_in[10];
    const float* Wn2  = (const float*)d_in[11];
    const float* bn2  = (const float*)d_in[12];
    const float* We2  = (const float*)d_in[13];
    const float* be2  = (const float*)d_in[14];
    const float* Wu2  = (const float*)d_in[15];
    const float* bu2  = (const float*)d_in[16];
    const float* g2   = (const float*)d_in[17];
    const float* beta2= (const float*)d_in[18];

    const int* srcI = ei;
    const int* dstI = ei + NE;

    float* out = (float*)d_out;
    float* nt   = (float*)d_ws;                   // N*128
    float* agg  = nt + (size_t)NN * 128;          // N*128
    float* cnt  = agg + (size_t)NN * 128;         // N
    float* invc = cnt + NN;                       // N
    float* h1 = out;                              // reuse d_out as layer-1 output

    const int gemm_grid = (NN + 63) / 64;

    // degree counts (shared by both layers)
    hipMemsetAsync(cnt, 0, NN * sizeof(float), stream);
    count_kernel<<<2048, 256, 0, stream>>>(dstI, cnt, NE);
    inv_kernel<<<(NN + 255) / 256, 256, 0, stream>>>(cnt, invc, NN);

    // ---- layer 1
    gemm_kernel<false, false><<<gemm_grid, 256, 0, stream>>>(
        x, nullptr, nullptr, Wn1, bn1, nullptr, nullptr, nt, NN, 128);
    hipMemsetAsync(agg, 0, (size_t)NN * 128 * sizeof(float), stream);
    msg_kernel<<<4096, 256, 0, stream>>>(ea, We1, be1, nt, srcI, dstI, agg, NE);
    gemm_kernel<true, true><<<gemm_grid, 256, 0, stream>>>(
        x, agg, invc, Wu1, bu1, g1, beta1, h1, NN, 256);

    // ---- layer 2
    gemm_kernel<false, false><<<gemm_grid, 256, 0, stream>>>(
        h1, nullptr, nullptr, Wn2, bn2, nullptr, nullptr, nt, NN, 128);
    hipMemsetAsync(agg, 0, (size_t)NN * 128 * sizeof(float), stream);
    msg_kernel<<<4096, 256, 0, stream>>>(ea, We2, be2, nt, srcI, dstI, agg, NE);
    gemm_kernel<true, true><<<gemm_grid, 256, 0, stream>>>(
        h1, agg, invc, Wu2, bu2, g2, beta2, out, NN, 256);
}

// Round 3
// 579.902 us; speedup vs baseline: 1.8783x; 1.8783x over previous
//
#include <hip/hip_runtime.h>

constexpr int NN = 100000;
constexpr int NE = 800000;
constexpr int SCAN_CHUNK = 512;
constexpr int NBLK = (NN + SCAN_CHUNK - 1) / SCAN_CHUNK;   // 196

// ---------------------------------------------------------------------------
// histogram of dst (int, exact -> deterministic)
__global__ __launch_bounds__(256)
void hist_kernel(const int* __restrict__ dst, int* __restrict__ hist, int E) {
    for (int i = blockIdx.x * blockDim.x + threadIdx.x; i < E;
         i += gridDim.x * blockDim.x)
        atomicAdd(&hist[dst[i]], 1);
}

// ---------------------------------------------------------------------------
// 3-kernel exclusive scan over hist[NN] -> row_ptr
__global__ __launch_bounds__(256)
void scan1_kernel(const int* __restrict__ hist, int* __restrict__ rp,
                  int* __restrict__ psum) {
    __shared__ int wsum[4];
    const int b = blockIdx.x, t = threadIdx.x;
    const int i0 = b * SCAN_CHUNK + 2 * t;
    int v0 = (i0     < NN) ? hist[i0]     : 0;
    int v1 = (i0 + 1 < NN) ? hist[i0 + 1] : 0;
    const int ts = v0 + v1;
    const int lane = t & 63, wid = t >> 6;
    int x = ts;
#pragma unroll
    for (int d = 1; d < 64; d <<= 1) {
        int n = __shfl_up(x, d, 64);
        if (lane >= d) x += n;
    }
    if (lane == 63) wsum[wid] = x;
    __syncthreads();
    int woff = (wid > 0 ? wsum[0] : 0) + (wid > 1 ? wsum[1] : 0) +
               (wid > 2 ? wsum[2] : 0);
    int incl = x + woff;
    int excl = incl - ts;
    if (i0     < NN) rp[i0]     = excl;
    if (i0 + 1 < NN) rp[i0 + 1] = excl + v0;
    if (t == 255) psum[b] = incl;
}

__global__ __launch_bounds__(256)
void scan2_kernel(int* __restrict__ psum) {   // single block, NBLK <= 256
    __shared__ int wsum[4];
    const int t = threadIdx.x;
    int v = (t < NBLK) ? psum[t] : 0;
    const int lane = t & 63, wid = t >> 6;
    int x = v;
#pragma unroll
    for (int d = 1; d < 64; d <<= 1) {
        int n = __shfl_up(x, d, 64);
        if (lane >= d) x += n;
    }
    if (lane == 63) wsum[wid] = x;
    __syncthreads();
    int woff = (wid > 0 ? wsum[0] : 0) + (wid > 1 ? wsum[1] : 0) +
               (wid > 2 ? wsum[2] : 0);
    if (t < NBLK) psum[t] = x + woff - v;     // exclusive
}

__global__ __launch_bounds__(256)
void scan3_kernel(int* __restrict__ rp, const int* __restrict__ psum) {
    const int b = blockIdx.x, t = threadIdx.x;
    const int off = psum[b];
    const int i0 = b * SCAN_CHUNK + 2 * t;
    if (i0     < NN) rp[i0]     += off;
    if (i0 + 1 < NN) rp[i0 + 1] += off;
    if (b == 0 && t == 0) rp[NN] = NE;
}

// ---------------------------------------------------------------------------
// bucket placement: eperm/ssrc sorted by dst
__global__ __launch_bounds__(256)
void place_kernel(const int* __restrict__ src, const int* __restrict__ dst,
                  const int* __restrict__ rp, int* __restrict__ fill,
                  int* __restrict__ eperm, int* __restrict__ ssrc, int E) {
    for (int e = blockIdx.x * blockDim.x + threadIdx.x; e < E;
         e += gridDim.x * blockDim.x) {
        int d = dst[e];
        int pos = rp[d] + atomicAdd(&fill[d], 1);
        eperm[pos] = e;
        ssrc[pos]  = src[e];
    }
}

// ---------------------------------------------------------------------------
// prep: P = Wn @ Wubot [128,128], Q = We @ Wubot [32,128], r = (bn+be)@Wubot
__global__ __launch_bounds__(256)
void prep_kernel(const float* __restrict__ Wn, const float* __restrict__ bn,
                 const float* __restrict__ We, const float* __restrict__ be,
                 const float* __restrict__ Wubot,
                 float* __restrict__ P, float* __restrict__ Q,
                 float* __restrict__ r) {
    int i = blockIdx.x * blockDim.x + threadIdx.x;
    if (i < 16384) {
        int row = i >> 7, col = i & 127;
        float s = 0.f;
        for (int m = 0; m < 128; m++) s = fmaf(Wn[row * 128 + m], Wubot[m * 128 + col], s);
        P[i] = s;
    } else if (i < 16384 + 4096) {
        int j = i - 16384;
        int row = j >> 7, col = j & 127;
        float s = 0.f;
        for (int m = 0; m < 128; m++) s = fmaf(We[row * 128 + m], Wubot[m * 128 + col], s);
        Q[j] = s;
    } else if (i < 16384 + 4096 + 128) {
        int col = i - 16384 - 4096;
        float s = 0.f;
        for (int m = 0; m < 128; m++) s = fmaf(bn[m] + be[m], Wubot[m * 128 + col], s);
        r[col] = s;
    }
}

// ---------------------------------------------------------------------------
// CSR aggregation: one wave per node. aggX[v] = sum x[src], aggE[v] = sum ea[e]
__global__ __launch_bounds__(256)
void agg_kernel(const float* __restrict__ X, const float* __restrict__ ea,
                const int* __restrict__ eperm, const int* __restrict__ ssrc,
                const int* __restrict__ rp,
                float* __restrict__ aggX, float* __restrict__ aggE,
                float* __restrict__ invc) {
    const int wid = threadIdx.x >> 6, lane = threadIdx.x & 63;
    const int v = blockIdx.x * 4 + wid;
    if (v >= NN) return;
    const int beg = rp[v], end = rp[v + 1];
    float a0 = 0.f, a1 = 0.f, aE = 0.f;
    int i = beg;
    for (; i + 1 < end; i += 2) {
        int s0 = ssrc[i], s1 = ssrc[i + 1];
        int e0 = eperm[i], e1 = eperm[i + 1];
        const float* p0 = &X[(size_t)s0 * 128];
        const float* p1 = &X[(size_t)s1 * 128];
        float x00 = p0[lane],      x10 = p1[lane];
        float x01 = p0[lane + 64], x11 = p1[lane + 64];
        float ev0 = 0.f, ev1 = 0.f;
        if (lane < 32) { ev0 = ea[(size_t)e0 * 32 + lane]; ev1 = ea[(size_t)e1 * 32 + lane]; }
        a0 += x00 + x10;
        a1 += x01 + x11;
        aE += ev0 + ev1;
    }
    if (i < end) {
        int s0 = ssrc[i], e0 = eperm[i];
        a0 += X[(size_t)s0 * 128 + lane];
        a1 += X[(size_t)s0 * 128 + lane + 64];
        if (lane < 32) aE += ea[(size_t)e0 * 32 + lane];
    }
    aggX[(size_t)v * 128 + lane]      = a0;
    aggX[(size_t)v * 128 + lane + 64] = a1;
    if (lane < 32) aggE[(size_t)v * 32 + lane] = aE;
    if (lane == 0) invc[v] = (end > beg) ? 1.0f / (float)(end - beg) : 0.0f;
}

// ---------------------------------------------------------------------------
// fused GEMM: C = LN(relu(X@Wt + invc*(aggX@P + aggE@Q) + has*r + bu), g, beta)
// K segments: [0,128)=X@Wt, [128,256)=aggX@P (row-scaled), [256,288)=aggE@Q
__global__ __launch_bounds__(256)
void gemmF_kernel(const float* __restrict__ X, const float* __restrict__ aggX,
                  const float* __restrict__ aggE, const float* __restrict__ invc,
                  const float* __restrict__ Wt, const float* __restrict__ P,
                  const float* __restrict__ Q, const float* __restrict__ r,
                  const float* __restrict__ bu, const float* __restrict__ g,
                  const float* __restrict__ beta, float* __restrict__ C, int M) {
    __shared__ float As[32][68];
    __shared__ float Bs[32][132];

    const int tid = threadIdx.x;
    const int tx = tid & 15;
    const int ty = tid >> 4;
    const int brow = blockIdx.x * 64;

    float acc[4][8];
#pragma unroll
    for (int i = 0; i < 4; i++)
#pragma unroll
        for (int j = 0; j < 8; j++) acc[i][j] = 0.0f;

    for (int k0 = 0; k0 < 288; k0 += 32) {
        // ---- stage A tile
#pragma unroll
        for (int j = 0; j < 2; j++) {
            int f = tid + j * 256;
            int rr = f >> 3;
            int kc = f & 7;
            int grow = brow + rr;
            float4 v = make_float4(0.f, 0.f, 0.f, 0.f);
            if (grow < M) {
                if (k0 < 128) {
                    v = *reinterpret_cast<const float4*>(
                        &X[(size_t)grow * 128 + k0 + kc * 4]);
                } else if (k0 < 256) {
                    v = *reinterpret_cast<const float4*>(
                        &aggX[(size_t)grow * 128 + (k0 - 128) + kc * 4]);
                    float s = invc[grow];
                    v.x *= s; v.y *= s; v.z *= s; v.w *= s;
                } else {
                    v = *reinterpret_cast<const float4*>(
                        &aggE[(size_t)grow * 32 + kc * 4]);
                    float s = invc[grow];
                    v.x *= s; v.y *= s; v.z *= s; v.w *= s;
                }
            }
            As[kc * 4 + 0][rr] = v.x;
            As[kc * 4 + 1][rr] = v.y;
            As[kc * 4 + 2][rr] = v.z;
            As[kc * 4 + 3][rr] = v.w;
        }
        // ---- stage B tile
        const float* Wp; int krow;
        if (k0 < 128)      { Wp = Wt; krow = k0; }
        else if (k0 < 256) { Wp = P;  krow = k0 - 128; }
        else               { Wp = Q;  krow = k0 - 256; }
#pragma unroll
        for (int j = 0; j < 4; j++) {
            int f = tid + j * 256;
            int kk = f >> 5;
            int col = (f & 31) * 4;
            *reinterpret_cast<float4*>(&Bs[kk][col]) =
                *reinterpret_cast<const float4*>(&Wp[(size_t)(krow + kk) * 128 + col]);
        }
        __syncthreads();

#pragma unroll
        for (int kk = 0; kk < 32; kk++) {
            float4 a4 = *reinterpret_cast<const float4*>(&As[kk][ty * 4]);
            float4 b0 = *reinterpret_cast<const float4*>(&Bs[kk][tx * 8]);
            float4 b1 = *reinterpret_cast<const float4*>(&Bs[kk][tx * 8 + 4]);
            float a[4] = {a4.x, a4.y, a4.z, a4.w};
            float b[8] = {b0.x, b0.y, b0.z, b0.w, b1.x, b1.y, b1.z, b1.w};
#pragma unroll
            for (int i = 0; i < 4; i++)
#pragma unroll
                for (int j = 0; j < 8; j++)
                    acc[i][j] = fmaf(a[i], b[j], acc[i][j]);
        }
        __syncthreads();
    }

    // ---- epilogue: +bu +has*r, relu, layernorm
    float bb[8], rr8[8], gg[8], be8[8];
#pragma unroll
    for (int j = 0; j < 8; j++) {
        bb[j]  = bu[tx * 8 + j];
        rr8[j] = r[tx * 8 + j];
        gg[j]  = g[tx * 8 + j];
        be8[j] = beta[tx * 8 + j];
    }
#pragma unroll
    for (int i = 0; i < 4; i++) {
        int grow = brow + ty * 4 + i;
        float hasv = 0.f;
        if (grow < M) hasv = (invc[grow] > 0.f) ? 1.f : 0.f;
        float v[8], s = 0.f, s2 = 0.f;
#pragma unroll
        for (int j = 0; j < 8; j++) {
            float t = fmaxf(acc[i][j] + bb[j] + hasv * rr8[j], 0.0f);
            v[j] = t; s += t; s2 += t * t;
        }
#pragma unroll
        for (int m = 1; m < 16; m <<= 1) {
            s  += __shfl_xor(s, m, 64);
            s2 += __shfl_xor(s2, m, 64);
        }
        float mean = s * (1.0f / 128.0f);
        float var  = s2 * (1.0f / 128.0f) - mean * mean;
        float rstd = rsqrtf(var + 1e-5f);
        if (grow < M) {
            float o[8];
#pragma unroll
            for (int j = 0; j < 8; j++)
                o[j] = (v[j] - mean) * rstd * gg[j] + be8[j];
            float4* p = reinterpret_cast<float4*>(&C[(size_t)grow * 128 + tx * 8]);
            p[0] = make_float4(o[0], o[1], o[2], o[3]);
            p[1] = make_float4(o[4], o[5], o[6], o[7]);
        }
    }
}

// ---------------------------------------------------------------------------
extern "C" void kernel_launch(void* const* d_in, const int* in_sizes, int n_in,
                              void* d_out, int out_size, void* d_ws, size_t ws_size,
                              hipStream_t stream)
{
    const float* x    = (const float*)d_in[0];
    const int*   ei   = (const int*)d_in[1];
    const float* ea   = (const float*)d_in[2];
    const float* Wn1  = (const float*)d_in[3];
    const float* bn1  = (const float*)d_in[4];
    const float* We1  = (const float*)d_in[5];
    const float* be1  = (const float*)d_in[6];
    const float* Wu1  = (const float*)d_in[7];
    const float* bu1  = (const float*)d_in[8];
    const float* g1   = (const float*)d_in[9];
    const float* beta1= (const float*)d_in[10];
    const float* Wn2  = (const float*)d_in[11];
    const float* bn2  = (const float*)d_in[12];
    const float* We2  = (const float*)d_in[13];
    const float* be2  = (const float*)d_in[14];
    const float* Wu2  = (const float*)d_in[15];
    const float* bu2  = (const float*)d_in[16];
    const float* g2   = (const float*)d_in[17];
    const float* beta2= (const float*)d_in[18];

    const int* srcI = ei;
    const int* dstI = ei + NE;

    float* out = (float*)d_out;
    float* h1  = out;                                  // layer-1 output reuses d_out

    // workspace layout
    float* aggX = (float*)d_ws;                        // N*128
    float* aggE = aggX + (size_t)NN * 128;             // N*32
    float* invc = aggE + (size_t)NN * 32;              // N
    int*   rp   = (int*)(invc + NN);                   // N+1
    int*   hist = rp + NN + 1;                         // N
    int*   fill = hist + NN;                           // N
    int*   psum = fill + NN;                           // 256
    int*   eperm= psum + 256;                          // E
    int*   ssrc = eperm + NE;                          // E
    float* P1   = (float*)(ssrc + NE);                 // 128*128
    float* Q1   = P1 + 16384;                          // 32*128
    float* r1   = Q1 + 4096;                           // 128
    float* P2   = r1 + 128;
    float* Q2   = P2 + 16384;
    float* r2   = Q2 + 4096;

    const int gemm_grid = (NN + 63) / 64;

    // ---- build CSR (counting sort by dst); shared by both layers
    hipMemsetAsync(hist, 0, NN * sizeof(int), stream);
    hipMemsetAsync(fill, 0, NN * sizeof(int), stream);
    hist_kernel<<<2048, 256, 0, stream>>>(dstI, hist, NE);
    scan1_kernel<<<NBLK, 256, 0, stream>>>(hist, rp, psum);
    scan2_kernel<<<1, 256, 0, stream>>>(psum);
    scan3_kernel<<<NBLK, 256, 0, stream>>>(rp, psum);
    place_kernel<<<2048, 256, 0, stream>>>(srcI, dstI, rp, fill, eperm, ssrc, NE);

    // ---- weight products (once)
    prep_kernel<<<81, 256, 0, stream>>>(Wn1, bn1, We1, be1, Wu1 + 128 * 128, P1, Q1, r1);
    prep_kernel<<<81, 256, 0, stream>>>(Wn2, bn2, We2, be2, Wu2 + 128 * 128, P2, Q2, r2);

    // ---- layer 1
    agg_kernel<<<(NN + 3) / 4, 256, 0, stream>>>(x, ea, eperm, ssrc, rp, aggX, aggE, invc);
    gemmF_kernel<<<gemm_grid, 256, 0, stream>>>(x, aggX, aggE, invc,
                                                Wu1, P1, Q1, r1, bu1, g1, beta1, h1, NN);
    // ---- layer 2
    agg_kernel<<<(NN + 3) / 4, 256, 0, stream>>>(h1, ea, eperm, ssrc, rp, aggX, aggE, invc);
    gemmF_kernel<<<gemm_grid, 256, 0, stream>>>(h1, aggX, aggE, invc,
                                                Wu2, P2, Q2, r2, bu2, g2, beta2, out, NN);
}

// Round 4
// 358.005 us; speedup vs baseline: 3.0425x; 1.6198x over previous
//
#include <hip/hip_runtime.h>

constexpr int NN = 100000;
constexpr int NE = 800000;
constexpr int SCAN_CHUNK = 512;
constexpr int NBLK = (NN + SCAN_CHUNK - 1) / SCAN_CHUNK;   // 196
constexpr int KTOT = 288;          // 128 (x) + 128 (mean) + 32 (aggE)
constexpr int NOCT = KTOT / 8;     // 36 k-octets

typedef short bf16x8 __attribute__((ext_vector_type(8)));
typedef float f32x4  __attribute__((ext_vector_type(4)));

__device__ inline ushort f2b(float f) {
    uint u = __builtin_bit_cast(uint, f);
    u += 0x7FFF + ((u >> 16) & 1);
    return (ushort)(u >> 16);
}
__device__ inline float b2f(ushort h) {
    uint u = (uint)h << 16;
    return __builtin_bit_cast(float, u);
}

// ---------------------------------------------------------------------------
__global__ __launch_bounds__(256)
void castx_kernel(const float* __restrict__ in, ushort* __restrict__ out) {
    // N*128 = 12.8M elems, 8 per thread
    size_t i = ((size_t)blockIdx.x * 256 + threadIdx.x) * 8;
    if (i >= (size_t)NN * 128) return;
    float4 v0 = *reinterpret_cast<const float4*>(&in[i]);
    float4 v1 = *reinterpret_cast<const float4*>(&in[i + 4]);
    ushort o[8] = {f2b(v0.x), f2b(v0.y), f2b(v0.z), f2b(v0.w),
                   f2b(v1.x), f2b(v1.y), f2b(v1.z), f2b(v1.w)};
    *reinterpret_cast<bf16x8*>(&out[i]) = *reinterpret_cast<bf16x8*>(o);
}

// ---------------------------------------------------------------------------
// CSR build (counting sort by dst) — unchanged from round 3
__global__ __launch_bounds__(256)
void hist_kernel(const int* __restrict__ dst, int* __restrict__ hist, int E) {
    for (int i = blockIdx.x * blockDim.x + threadIdx.x; i < E;
         i += gridDim.x * blockDim.x)
        atomicAdd(&hist[dst[i]], 1);
}

__global__ __launch_bounds__(256)
void scan1_kernel(const int* __restrict__ hist, int* __restrict__ rp,
                  int* __restrict__ psum) {
    __shared__ int wsum[4];
    const int b = blockIdx.x, t = threadIdx.x;
    const int i0 = b * SCAN_CHUNK + 2 * t;
    int v0 = (i0     < NN) ? hist[i0]     : 0;
    int v1 = (i0 + 1 < NN) ? hist[i0 + 1] : 0;
    const int ts = v0 + v1;
    const int lane = t & 63, wid = t >> 6;
    int x = ts;
#pragma unroll
    for (int d = 1; d < 64; d <<= 1) {
        int n = __shfl_up(x, d, 64);
        if (lane >= d) x += n;
    }
    if (lane == 63) wsum[wid] = x;
    __syncthreads();
    int woff = (wid > 0 ? wsum[0] : 0) + (wid > 1 ? wsum[1] : 0) +
               (wid > 2 ? wsum[2] : 0);
    int incl = x + woff;
    int excl = incl - ts;
    if (i0     < NN) rp[i0]     = excl;
    if (i0 + 1 < NN) rp[i0 + 1] = excl + v0;
    if (t == 255) psum[b] = incl;
}

__global__ __launch_bounds__(256)
void scan2_kernel(int* __restrict__ psum) {
    __shared__ int wsum[4];
    const int t = threadIdx.x;
    int v = (t < NBLK) ? psum[t] : 0;
    const int lane = t & 63, wid = t >> 6;
    int x = v;
#pragma unroll
    for (int d = 1; d < 64; d <<= 1) {
        int n = __shfl_up(x, d, 64);
        if (lane >= d) x += n;
    }
    if (lane == 63) wsum[wid] = x;
    __syncthreads();
    int woff = (wid > 0 ? wsum[0] : 0) + (wid > 1 ? wsum[1] : 0) +
               (wid > 2 ? wsum[2] : 0);
    if (t < NBLK) psum[t] = x + woff - v;
}

__global__ __launch_bounds__(256)
void scan3_kernel(int* __restrict__ rp, const int* __restrict__ psum) {
    const int b = blockIdx.x, t = threadIdx.x;
    const int off = psum[b];
    const int i0 = b * SCAN_CHUNK + 2 * t;
    if (i0     < NN) rp[i0]     += off;
    if (i0 + 1 < NN) rp[i0 + 1] += off;
    if (b == 0 && t == 0) rp[NN] = NE;
}

__global__ __launch_bounds__(256)
void place_kernel(const int* __restrict__ src, const int* __restrict__ dst,
                  const int* __restrict__ rp, int* __restrict__ fill,
                  int* __restrict__ eperm, int* __restrict__ ssrc, int E) {
    for (int e = blockIdx.x * blockDim.x + threadIdx.x; e < E;
         e += gridDim.x * blockDim.x) {
        int d = dst[e];
        int pos = rp[d] + atomicAdd(&fill[d], 1);
        eperm[pos] = e;
        ssrc[pos]  = src[e];
    }
}

// ---------------------------------------------------------------------------
// prep: build pre-transposed bf16 B  Btp[NOCT][128][8] for the fused GEMM:
//   K<128:        Wu[K][col]              (x part of update weight)
//   128<=K<256:   (Wn @ Wubot)[K-128][col]
//   256<=K<288:   (We @ Wubot)[K-256][col]
// plus r[col] = (bn+be) @ Wubot
__global__ __launch_bounds__(256)
void prep_kernel(const float* __restrict__ Wn, const float* __restrict__ bn,
                 const float* __restrict__ We, const float* __restrict__ be,
                 const float* __restrict__ Wu,
                 ushort* __restrict__ Btp, float* __restrict__ r) {
    int i = blockIdx.x * blockDim.x + threadIdx.x;
    if (i < KTOT * 128) {
        int K = i >> 7, col = i & 127;
        float v;
        if (K < 128) {
            v = Wu[(size_t)K * 128 + col];
        } else if (K < 256) {
            const float* Wubot = Wu + 128 * 128;
            float s = 0.f;
            for (int m = 0; m < 128; m++)
                s = fmaf(Wn[(K - 128) * 128 + m], Wubot[m * 128 + col], s);
            v = s;
        } else {
            const float* Wubot = Wu + 128 * 128;
            float s = 0.f;
            for (int m = 0; m < 128; m++)
                s = fmaf(We[(K - 256) * 128 + m], Wubot[m * 128 + col], s);
            v = s;
        }
        Btp[(size_t)(K >> 3) * 1024 + col * 8 + (K & 7)] = f2b(v);
    } else if (i < KTOT * 128 + 128) {
        int col = i - KTOT * 128;
        const float* Wubot = Wu + 128 * 128;
        float s = 0.f;
        for (int m = 0; m < 128; m++)
            s = fmaf(bn[m] + be[m], Wubot[m * 128 + col], s);
        r[col] = s;
    }
}

// ---------------------------------------------------------------------------
// CSR aggregation over bf16 feature table.
// meanb[v] = (sum_{e} Xb[src]) * invc   (bf16), aggEb[v] = (sum ea[e]) * invc
__global__ __launch_bounds__(256)
void agg_kernel(const ushort* __restrict__ Xb, const float* __restrict__ ea,
                const int* __restrict__ eperm, const int* __restrict__ ssrc,
                const int* __restrict__ rp,
                ushort* __restrict__ meanb, ushort* __restrict__ aggEb,
                float* __restrict__ invc) {
    const int wid = threadIdx.x >> 6, lane = threadIdx.x & 63;
    const int v = blockIdx.x * 4 + wid;
    if (v >= NN) return;
    const int beg = rp[v], end = rp[v + 1];
    float a0 = 0.f, a1 = 0.f, aE = 0.f;
    int i = beg;
    for (; i + 3 < end; i += 4) {
        int s0 = ssrc[i], s1 = ssrc[i + 1], s2 = ssrc[i + 2], s3 = ssrc[i + 3];
        uint q0 = *reinterpret_cast<const uint*>(Xb + (size_t)s0 * 128 + lane * 2);
        uint q1 = *reinterpret_cast<const uint*>(Xb + (size_t)s1 * 128 + lane * 2);
        uint q2 = *reinterpret_cast<const uint*>(Xb + (size_t)s2 * 128 + lane * 2);
        uint q3 = *reinterpret_cast<const uint*>(Xb + (size_t)s3 * 128 + lane * 2);
        a0 += b2f((ushort)q0) + b2f((ushort)q1) + b2f((ushort)q2) + b2f((ushort)q3);
        a1 += b2f((ushort)(q0 >> 16)) + b2f((ushort)(q1 >> 16)) +
              b2f((ushort)(q2 >> 16)) + b2f((ushort)(q3 >> 16));
        if (lane < 32) {
            aE += ea[(size_t)eperm[i]     * 32 + lane] +
                  ea[(size_t)eperm[i + 1] * 32 + lane] +
                  ea[(size_t)eperm[i + 2] * 32 + lane] +
                  ea[(size_t)eperm[i + 3] * 32 + lane];
        }
    }
    for (; i < end; i++) {
        int s0 = ssrc[i];
        uint q0 = *reinterpret_cast<const uint*>(Xb + (size_t)s0 * 128 + lane * 2);
        a0 += b2f((ushort)q0);
        a1 += b2f((ushort)(q0 >> 16));
        if (lane < 32) aE += ea[(size_t)eperm[i] * 32 + lane];
    }
    float inv = (end > beg) ? 1.0f / (float)(end - beg) : 0.0f;
    uint pk = (uint)f2b(a0 * inv) | ((uint)f2b(a1 * inv) << 16);
    *reinterpret_cast<uint*>(meanb + (size_t)v * 128 + lane * 2) = pk;
    if (lane < 32) aggEb[(size_t)v * 32 + lane] = f2b(aE * inv);
    if (lane == 0) invc[v] = inv;
}

// ---------------------------------------------------------------------------
// fused MFMA GEMM: C = LN(relu(Abig @ B + bu + has*r), g, beta)
// Abig rows: [Xb | meanb | aggEb] (all bf16, invc pre-applied), K=288.
// 64-row tile, 4 waves in 2x2 (rows x cols) grid, 16x16x32 bf16 MFMA.
template<bool OUT_BF16>
__global__ __launch_bounds__(256)
void gemmF_kernel(const ushort* __restrict__ Xb, const ushort* __restrict__ meanb,
                  const ushort* __restrict__ aggEb, const float* __restrict__ invc,
                  const ushort* __restrict__ Btp, const float* __restrict__ r,
                  const float* __restrict__ bu, const float* __restrict__ g,
                  const float* __restrict__ beta,
                  float* __restrict__ Cf, ushort* __restrict__ Cb, int M) {
    __shared__ ushort Als[4][64][8];     // 4KB  [k-octet][row][8k]
    __shared__ ushort Bls[4][128][8];    // 8KB  [k-octet][col][8k]
    __shared__ float ps[2][64], ps2[2][64];

    const int tid = threadIdx.x;
    const int wid = tid >> 6, lane = tid & 63;
    const int wr = wid >> 1, wc = wid & 1;
    const int lo4 = lane >> 4, li = lane & 15;
    const int brow = blockIdx.x * 64;

    f32x4 acc[2][4];
#pragma unroll
    for (int fr = 0; fr < 2; fr++)
#pragma unroll
        for (int fc = 0; fc < 4; fc++) acc[fr][fc] = (f32x4)0.f;

    const int arow = tid & 63;      // staging row
    const int akc  = tid >> 6;      // staging k-octet (0..3)
    const int grow = brow + arow;

    for (int step = 0; step < 9; step++) {
        // ---- stage A: 64 rows x 32 k (one bf16x8 per thread)
        {
            int kg = step * 4 + akc;    // global k-octet 0..35
            bf16x8 v = (bf16x8)0;
            if (grow < M) {
                if (kg < 16)
                    v = *reinterpret_cast<const bf16x8*>(Xb + (size_t)grow * 128 + kg * 8);
                else if (kg < 32)
                    v = *reinterpret_cast<const bf16x8*>(meanb + (size_t)grow * 128 + (kg - 16) * 8);
                else
                    v = *reinterpret_cast<const bf16x8*>(aggEb + (size_t)grow * 32 + (kg - 32) * 8);
            }
            *reinterpret_cast<bf16x8*>(&Als[akc][arow][0]) = v;
        }
        // ---- stage B: 4 octets x 128 cols (two bf16x8 per thread)
#pragma unroll
        for (int h = 0; h < 2; h++) {
            int u = tid + h * 256;          // 0..511
            int kcl = u >> 7, col = u & 127;
            *reinterpret_cast<bf16x8*>(&Bls[kcl][col][0]) =
                *reinterpret_cast<const bf16x8*>(
                    Btp + ((size_t)(step * 4 + kcl) * 128 + col) * 8);
        }
        __syncthreads();

        bf16x8 a0 = *reinterpret_cast<const bf16x8*>(&Als[lo4][wr * 32 + li][0]);
        bf16x8 a1 = *reinterpret_cast<const bf16x8*>(&Als[lo4][wr * 32 + 16 + li][0]);
#pragma unroll
        for (int fc = 0; fc < 4; fc++) {
            bf16x8 b = *reinterpret_cast<const bf16x8*>(&Bls[lo4][wc * 64 + fc * 16 + li][0]);
            acc[0][fc] = __builtin_amdgcn_mfma_f32_16x16x32_bf16(a0, b, acc[0][fc], 0, 0, 0);
            acc[1][fc] = __builtin_amdgcn_mfma_f32_16x16x32_bf16(a1, b, acc[1][fc], 0, 0, 0);
        }
        __syncthreads();
    }

    // ---- epilogue: bias + has*r, relu, two-wave layernorm, store
    float bu8[4], r8[4], g8[4], be8[4];
#pragma unroll
    for (int fc = 0; fc < 4; fc++) {
        int col = wc * 64 + fc * 16 + li;
        bu8[fc] = bu[col]; r8[fc] = r[col]; g8[fc] = g[col]; be8[fc] = beta[col];
    }

    float sv[2][4], s2v[2][4], hasv[2][4];
#pragma unroll
    for (int fr = 0; fr < 2; fr++)
#pragma unroll
        for (int j = 0; j < 4; j++) {
            int gr = brow + wr * 32 + fr * 16 + lo4 * 4 + j;
            float hv = 0.f;
            if (gr < M) hv = (invc[gr] > 0.f) ? 1.f : 0.f;
            hasv[fr][j] = hv;
            float s = 0.f, s2 = 0.f;
#pragma unroll
            for (int fc = 0; fc < 4; fc++) {
                float val = acc[fr][fc][j] + bu8[fc] + hv * r8[fc];
                val = fmaxf(val, 0.f);
                acc[fr][fc][j] = val;
                s += val; s2 += val * val;
            }
#pragma unroll
            for (int m = 1; m < 16; m <<= 1) {
                s  += __shfl_xor(s, m, 64);
                s2 += __shfl_xor(s2, m, 64);
            }
            sv[fr][j] = s; s2v[fr][j] = s2;
        }

    if (li == 0) {
#pragma unroll
        for (int fr = 0; fr < 2; fr++)
#pragma unroll
            for (int j = 0; j < 4; j++) {
                int row64 = wr * 32 + fr * 16 + lo4 * 4 + j;
                ps[wc][row64]  = sv[fr][j];
                ps2[wc][row64] = s2v[fr][j];
            }
    }
    __syncthreads();

#pragma unroll
    for (int fr = 0; fr < 2; fr++)
#pragma unroll
        for (int j = 0; j < 4; j++) {
            int row64 = wr * 32 + fr * 16 + lo4 * 4 + j;
            int gr = brow + row64;
            float s  = sv[fr][j]  + ps[1 - wc][row64];
            float s2 = s2v[fr][j] + ps2[1 - wc][row64];
            float mean = s * (1.0f / 128.0f);
            float var  = s2 * (1.0f / 128.0f) - mean * mean;
            float rstd = rsqrtf(var + 1e-5f);
            if (gr < M) {
#pragma unroll
                for (int fc = 0; fc < 4; fc++) {
                    int col = wc * 64 + fc * 16 + li;
                    float o = (acc[fr][fc][j] - mean) * rstd * g8[fc] + be8[fc];
                    if (OUT_BF16) Cb[(size_t)gr * 128 + col] = f2b(o);
                    else          Cf[(size_t)gr * 128 + col] = o;
                }
            }
        }
}

// ---------------------------------------------------------------------------
extern "C" void kernel_launch(void* const* d_in, const int* in_sizes, int n_in,
                              void* d_out, int out_size, void* d_ws, size_t ws_size,
                              hipStream_t stream)
{
    const float* x    = (const float*)d_in[0];
    const int*   ei   = (const int*)d_in[1];
    const float* ea   = (const float*)d_in[2];
    const float* Wn1  = (const float*)d_in[3];
    const float* bn1  = (const float*)d_in[4];
    const float* We1  = (const float*)d_in[5];
    const float* be1  = (const float*)d_in[6];
    const float* Wu1  = (const float*)d_in[7];
    const float* bu1  = (const float*)d_in[8];
    const float* g1   = (const float*)d_in[9];
    const float* beta1= (const float*)d_in[10];
    const float* Wn2  = (const float*)d_in[11];
    const float* bn2  = (const float*)d_in[12];
    const float* We2  = (const float*)d_in[13];
    const float* be2  = (const float*)d_in[14];
    const float* Wu2  = (const float*)d_in[15];
    const float* bu2  = (const float*)d_in[16];
    const float* g2   = (const float*)d_in[17];
    const float* beta2= (const float*)d_in[18];

    const int* srcI = ei;
    const int* dstI = ei + NE;
    float* out = (float*)d_out;

    // ---- workspace layout
    float* invc = (float*)d_ws;                        // N
    int*   rp   = (int*)(invc + NN);                   // N+1
    int*   hist = rp + NN + 1;                         // N
    int*   fill = hist + NN;                           // N
    int*   psum = fill + NN;                           // 256
    int*   eperm= psum + 256;                          // E
    int*   ssrc = eperm + NE;                          // E
    uintptr_t base = ((uintptr_t)(ssrc + NE) + 15) & ~(uintptr_t)15;
    ushort* Xb    = (ushort*)base;                     // N*128 (also h1 bf16)
    ushort* meanb = Xb + (size_t)NN * 128;             // N*128
    ushort* aggEb = meanb + (size_t)NN * 128;          // N*32
    ushort* Btp1  = aggEb + (size_t)NN * 32;           // 36*128*8
    ushort* Btp2  = Btp1 + NOCT * 1024;
    float*  r1    = (float*)(Btp2 + NOCT * 1024);      // 128
    float*  r2    = r1 + 128;

    const int gemm_grid = (NN + 63) / 64;

    // ---- bf16 feature table
    castx_kernel<<<(int)(((size_t)NN * 128 / 8 + 255) / 256), 256, 0, stream>>>(x, Xb);

    // ---- CSR build (shared by both layers)
    hipMemsetAsync(hist, 0, NN * sizeof(int), stream);
    hipMemsetAsync(fill, 0, NN * sizeof(int), stream);
    hist_kernel<<<2048, 256, 0, stream>>>(dstI, hist, NE);
    scan1_kernel<<<NBLK, 256, 0, stream>>>(hist, rp, psum);
    scan2_kernel<<<1, 256, 0, stream>>>(psum);
    scan3_kernel<<<NBLK, 256, 0, stream>>>(rp, psum);
    place_kernel<<<2048, 256, 0, stream>>>(srcI, dstI, rp, fill, eperm, ssrc, NE);

    // ---- weight products (once)
    prep_kernel<<<(KTOT * 128 + 128 + 255) / 256, 256, 0, stream>>>(
        Wn1, bn1, We1, be1, Wu1, Btp1, r1);
    prep_kernel<<<(KTOT * 128 + 128 + 255) / 256, 256, 0, stream>>>(
        Wn2, bn2, We2, be2, Wu2, Btp2, r2);

    // ---- layer 1 (h1 written bf16 in place of Xb region's successor use)
    agg_kernel<<<(NN + 3) / 4, 256, 0, stream>>>(Xb, ea, eperm, ssrc, rp,
                                                 meanb, aggEb, invc);
    gemmF_kernel<true><<<gemm_grid, 256, 0, stream>>>(
        Xb, meanb, aggEb, invc, Btp1, r1, bu1, g1, beta1, nullptr, Xb, NN);

    // ---- layer 2 (Xb now holds h1 bf16)
    agg_kernel<<<(NN + 3) / 4, 256, 0, stream>>>(Xb, ea, eperm, ssrc, rp,
                                                 meanb, aggEb, invc);
    gemmF_kernel<false><<<gemm_grid, 256, 0, stream>>>(
        Xb, meanb, aggEb, invc, Btp2, r2, bu2, g2, beta2, out, nullptr, NN);
}

// Round 5
// 317.648 us; speedup vs baseline: 3.4290x; 1.1270x over previous
//
#include <hip/hip_runtime.h>

constexpr int NN = 100000;
constexpr int NE = 800000;
constexpr int SCAN_CHUNK = 512;
constexpr int NBLK = (NN + SCAN_CHUNK - 1) / SCAN_CHUNK;   // 196
constexpr int KTOT = 288;          // 128 (x) + 128 (mean) + 32 (aggE)
constexpr int NOCT = KTOT / 8;     // 36 k-octets

typedef short bf16x8 __attribute__((ext_vector_type(8)));
typedef float f32x4  __attribute__((ext_vector_type(4)));

__device__ inline ushort f2b(float f) {
    uint u = __builtin_bit_cast(uint, f);
    u += 0x7FFF + ((u >> 16) & 1);
    return (ushort)(u >> 16);
}
__device__ inline float b2f(ushort h) {
    uint u = (uint)h << 16;
    return __builtin_bit_cast(float, u);
}

// ---------------------------------------------------------------------------
__global__ __launch_bounds__(256)
void castx_kernel(const float* __restrict__ in, ushort* __restrict__ out) {
    size_t i = ((size_t)blockIdx.x * 256 + threadIdx.x) * 8;
    if (i >= (size_t)NN * 128) return;
    float4 v0 = *reinterpret_cast<const float4*>(&in[i]);
    float4 v1 = *reinterpret_cast<const float4*>(&in[i + 4]);
    ushort o[8] = {f2b(v0.x), f2b(v0.y), f2b(v0.z), f2b(v0.w),
                   f2b(v1.x), f2b(v1.y), f2b(v1.z), f2b(v1.w)};
    *reinterpret_cast<bf16x8*>(&out[i]) = *reinterpret_cast<bf16x8*>(o);
}

// ---------------------------------------------------------------------------
// CSR build (counting sort by dst)
__global__ __launch_bounds__(256)
void hist_kernel(const int* __restrict__ dst, int* __restrict__ hist, int E) {
    for (int i = blockIdx.x * blockDim.x + threadIdx.x; i < E;
         i += gridDim.x * blockDim.x)
        atomicAdd(&hist[dst[i]], 1);
}

__global__ __launch_bounds__(256)
void scan1_kernel(const int* __restrict__ hist, int* __restrict__ rp,
                  int* __restrict__ psum) {
    __shared__ int wsum[4];
    const int b = blockIdx.x, t = threadIdx.x;
    const int i0 = b * SCAN_CHUNK + 2 * t;
    int v0 = (i0     < NN) ? hist[i0]     : 0;
    int v1 = (i0 + 1 < NN) ? hist[i0 + 1] : 0;
    const int ts = v0 + v1;
    const int lane = t & 63, wid = t >> 6;
    int x = ts;
#pragma unroll
    for (int d = 1; d < 64; d <<= 1) {
        int n = __shfl_up(x, d, 64);
        if (lane >= d) x += n;
    }
    if (lane == 63) wsum[wid] = x;
    __syncthreads();
    int woff = (wid > 0 ? wsum[0] : 0) + (wid > 1 ? wsum[1] : 0) +
               (wid > 2 ? wsum[2] : 0);
    int incl = x + woff;
    int excl = incl - ts;
    if (i0     < NN) rp[i0]     = excl;
    if (i0 + 1 < NN) rp[i0 + 1] = excl + v0;
    if (t == 255) psum[b] = incl;
}

__global__ __launch_bounds__(256)
void scan2_kernel(int* __restrict__ psum) {
    __shared__ int wsum[4];
    const int t = threadIdx.x;
    int v = (t < NBLK) ? psum[t] : 0;
    const int lane = t & 63, wid = t >> 6;
    int x = v;
#pragma unroll
    for (int d = 1; d < 64; d <<= 1) {
        int n = __shfl_up(x, d, 64);
        if (lane >= d) x += n;
    }
    if (lane == 63) wsum[wid] = x;
    __syncthreads();
    int woff = (wid > 0 ? wsum[0] : 0) + (wid > 1 ? wsum[1] : 0) +
               (wid > 2 ? wsum[2] : 0);
    if (t < NBLK) psum[t] = x + woff - v;
}

__global__ __launch_bounds__(256)
void scan3_kernel(int* __restrict__ rp, const int* __restrict__ psum) {
    const int b = blockIdx.x, t = threadIdx.x;
    const int off = psum[b];
    const int i0 = b * SCAN_CHUNK + 2 * t;
    if (i0     < NN) rp[i0]     += off;
    if (i0 + 1 < NN) rp[i0 + 1] += off;
    if (b == 0 && t == 0) rp[NN] = NE;
}

__global__ __launch_bounds__(256)
void place_kernel(const int* __restrict__ src, const int* __restrict__ dst,
                  const int* __restrict__ rp, int* __restrict__ fill,
                  int* __restrict__ eperm, int* __restrict__ ssrc, int E) {
    for (int e = blockIdx.x * blockDim.x + threadIdx.x; e < E;
         e += gridDim.x * blockDim.x) {
        int d = dst[e];
        int pos = rp[d] + atomicAdd(&fill[d], 1);
        eperm[pos] = e;
        ssrc[pos]  = src[e];
    }
}

// ---------------------------------------------------------------------------
// prep: pre-transposed bf16 B Btp[NOCT][128][8] + r vector (unchanged)
__global__ __launch_bounds__(256)
void prep_kernel(const float* __restrict__ Wn, const float* __restrict__ bn,
                 const float* __restrict__ We, const float* __restrict__ be,
                 const float* __restrict__ Wu,
                 ushort* __restrict__ Btp, float* __restrict__ r) {
    int i = blockIdx.x * blockDim.x + threadIdx.x;
    if (i < KTOT * 128) {
        int K = i >> 7, col = i & 127;
        float v;
        if (K < 128) {
            v = Wu[(size_t)K * 128 + col];
        } else if (K < 256) {
            const float* Wubot = Wu + 128 * 128;
            float s = 0.f;
            for (int m = 0; m < 128; m++)
                s = fmaf(Wn[(K - 128) * 128 + m], Wubot[m * 128 + col], s);
            v = s;
        } else {
            const float* Wubot = Wu + 128 * 128;
            float s = 0.f;
            for (int m = 0; m < 128; m++)
                s = fmaf(We[(K - 256) * 128 + m], Wubot[m * 128 + col], s);
            v = s;
        }
        Btp[(size_t)(K >> 3) * 1024 + col * 8 + (K & 7)] = f2b(v);
    } else if (i < KTOT * 128 + 128) {
        int col = i - KTOT * 128;
        const float* Wubot = Wu + 128 * 128;
        float s = 0.f;
        for (int m = 0; m < 128; m++)
            s = fmaf(bn[m] + be[m], Wubot[m * 128 + col], s);
        r[col] = s;
    }
}

// ---------------------------------------------------------------------------
// CSR aggregation, edge-pair scheme: lanes 0-31 handle even edge, 32-63 odd.
// One dwordx2 per lane covers TWO 256B Xb rows; one dword covers TWO ea rows.
// DO_EA: also aggregate edge_attr (layer-invariant -> only layer 1) + invc.
template<bool DO_EA>
__global__ __launch_bounds__(256)
void agg_kernel(const ushort* __restrict__ Xb, const float* __restrict__ ea,
                const int* __restrict__ eperm, const int* __restrict__ ssrc,
                const int* __restrict__ rp,
                ushort* __restrict__ meanb, ushort* __restrict__ aggEb,
                float* __restrict__ invc) {
    const int wid  = __builtin_amdgcn_readfirstlane(threadIdx.x >> 6);
    const int lane = threadIdx.x & 63;
    const int v = blockIdx.x * 4 + wid;
    if (v >= NN) return;
    const int beg = __builtin_amdgcn_readfirstlane(rp[v]);
    const int end = __builtin_amdgcn_readfirstlane(rp[v + 1]);
    const int half = lane >> 5;          // which edge of the pair
    const int l32  = lane & 31;

    float a0 = 0.f, a1 = 0.f, a2 = 0.f, a3 = 0.f;   // features l32*4..+3
    float aE = 0.f;                                  // feature l32
    int i = beg;
    // ---- 4 edges per iteration (2 pair-loads)
    for (; i + 3 < end; i += 4) {
        int s0 = __builtin_amdgcn_readfirstlane(ssrc[i]);
        int s1 = __builtin_amdgcn_readfirstlane(ssrc[i + 1]);
        int s2 = __builtin_amdgcn_readfirstlane(ssrc[i + 2]);
        int s3 = __builtin_amdgcn_readfirstlane(ssrc[i + 3]);
        int sA = half ? s1 : s0;
        int sB = half ? s3 : s2;
        uint2 qA = *reinterpret_cast<const uint2*>(Xb + (size_t)sA * 128 + l32 * 4);
        uint2 qB = *reinterpret_cast<const uint2*>(Xb + (size_t)sB * 128 + l32 * 4);
        if (DO_EA) {
            int e0 = __builtin_amdgcn_readfirstlane(eperm[i]);
            int e1 = __builtin_amdgcn_readfirstlane(eperm[i + 1]);
            int e2 = __builtin_amdgcn_readfirstlane(eperm[i + 2]);
            int e3 = __builtin_amdgcn_readfirstlane(eperm[i + 3]);
            int eA = half ? e1 : e0;
            int eB = half ? e3 : e2;
            aE += ea[(size_t)eA * 32 + l32] + ea[(size_t)eB * 32 + l32];
        }
        a0 += b2f((ushort)qA.x) + b2f((ushort)qB.x);
        a1 += b2f((ushort)(qA.x >> 16)) + b2f((ushort)(qB.x >> 16));
        a2 += b2f((ushort)qA.y) + b2f((ushort)qB.y);
        a3 += b2f((ushort)(qA.y >> 16)) + b2f((ushort)(qB.y >> 16));
    }
    // ---- 2-edge step
    if (i + 1 < end) {
        int s0 = __builtin_amdgcn_readfirstlane(ssrc[i]);
        int s1 = __builtin_amdgcn_readfirstlane(ssrc[i + 1]);
        int sA = half ? s1 : s0;
        uint2 qA = *reinterpret_cast<const uint2*>(Xb + (size_t)sA * 128 + l32 * 4);
        if (DO_EA) {
            int e0 = __builtin_amdgcn_readfirstlane(eperm[i]);
            int e1 = __builtin_amdgcn_readfirstlane(eperm[i + 1]);
            int eA = half ? e1 : e0;
            aE += ea[(size_t)eA * 32 + l32];
        }
        a0 += b2f((ushort)qA.x);
        a1 += b2f((ushort)(qA.x >> 16));
        a2 += b2f((ushort)qA.y);
        a3 += b2f((ushort)(qA.y >> 16));
        i += 2;
    }
    // ---- 1-edge tail (only lanes of half 0 contribute)
    if (i < end) {
        int s0 = __builtin_amdgcn_readfirstlane(ssrc[i]);
        if (half == 0) {
            uint2 qA = *reinterpret_cast<const uint2*>(Xb + (size_t)s0 * 128 + l32 * 4);
            a0 += b2f((ushort)qA.x);
            a1 += b2f((ushort)(qA.x >> 16));
            a2 += b2f((ushort)qA.y);
            a3 += b2f((ushort)(qA.y >> 16));
            if (DO_EA) {
                int e0 = __builtin_amdgcn_readfirstlane(eperm[i]);
                aE += ea[(size_t)e0 * 32 + l32];
            }
        }
    }
    // ---- combine halves
    a0 += __shfl_xor(a0, 32, 64);
    a1 += __shfl_xor(a1, 32, 64);
    a2 += __shfl_xor(a2, 32, 64);
    a3 += __shfl_xor(a3, 32, 64);
    if (DO_EA) aE += __shfl_xor(aE, 32, 64);

    float inv = (end > beg) ? 1.0f / (float)(end - beg) : 0.0f;
    if (half == 0) {
        uint lo = (uint)f2b(a0 * inv) | ((uint)f2b(a1 * inv) << 16);
        uint hi = (uint)f2b(a2 * inv) | ((uint)f2b(a3 * inv) << 16);
        *reinterpret_cast<uint2*>(meanb + (size_t)v * 128 + l32 * 4) =
            make_uint2(lo, hi);
        if (DO_EA) aggEb[(size_t)v * 32 + l32] = f2b(aE * inv);
    }
    if (DO_EA && lane == 0) invc[v] = inv;
}

// ---------------------------------------------------------------------------
// fused MFMA GEMM: C = LN(relu(Abig @ B + bu + has*r), g, beta)  (unchanged)
template<bool OUT_BF16>
__global__ __launch_bounds__(256)
void gemmF_kernel(const ushort* __restrict__ Xb, const ushort* __restrict__ meanb,
                  const ushort* __restrict__ aggEb, const float* __restrict__ invc,
                  const ushort* __restrict__ Btp, const float* __restrict__ r,
                  const float* __restrict__ bu, const float* __restrict__ g,
                  const float* __restrict__ beta,
                  float* __restrict__ Cf, ushort* __restrict__ Cb, int M) {
    __shared__ ushort Als[4][64][8];
    __shared__ ushort Bls[4][128][8];
    __shared__ float ps[2][64], ps2[2][64];

    const int tid = threadIdx.x;
    const int wid = tid >> 6, lane = tid & 63;
    const int wr = wid >> 1, wc = wid & 1;
    const int lo4 = lane >> 4, li = lane & 15;
    const int brow = blockIdx.x * 64;

    f32x4 acc[2][4];
#pragma unroll
    for (int fr = 0; fr < 2; fr++)
#pragma unroll
        for (int fc = 0; fc < 4; fc++) acc[fr][fc] = (f32x4)0.f;

    const int arow = tid & 63;
    const int akc  = tid >> 6;
    const int grow = brow + arow;

    for (int step = 0; step < 9; step++) {
        {
            int kg = step * 4 + akc;
            bf16x8 v = (bf16x8)0;
            if (grow < M) {
                if (kg < 16)
                    v = *reinterpret_cast<const bf16x8*>(Xb + (size_t)grow * 128 + kg * 8);
                else if (kg < 32)
                    v = *reinterpret_cast<const bf16x8*>(meanb + (size_t)grow * 128 + (kg - 16) * 8);
                else
                    v = *reinterpret_cast<const bf16x8*>(aggEb + (size_t)grow * 32 + (kg - 32) * 8);
            }
            *reinterpret_cast<bf16x8*>(&Als[akc][arow][0]) = v;
        }
#pragma unroll
        for (int h = 0; h < 2; h++) {
            int u = tid + h * 256;
            int kcl = u >> 7, col = u & 127;
            *reinterpret_cast<bf16x8*>(&Bls[kcl][col][0]) =
                *reinterpret_cast<const bf16x8*>(
                    Btp + ((size_t)(step * 4 + kcl) * 128 + col) * 8);
        }
        __syncthreads();

        bf16x8 a0 = *reinterpret_cast<const bf16x8*>(&Als[lo4][wr * 32 + li][0]);
        bf16x8 a1 = *reinterpret_cast<const bf16x8*>(&Als[lo4][wr * 32 + 16 + li][0]);
#pragma unroll
        for (int fc = 0; fc < 4; fc++) {
            bf16x8 b = *reinterpret_cast<const bf16x8*>(&Bls[lo4][wc * 64 + fc * 16 + li][0]);
            acc[0][fc] = __builtin_amdgcn_mfma_f32_16x16x32_bf16(a0, b, acc[0][fc], 0, 0, 0);
            acc[1][fc] = __builtin_amdgcn_mfma_f32_16x16x32_bf16(a1, b, acc[1][fc], 0, 0, 0);
        }
        __syncthreads();
    }

    float bu8[4], r8[4], g8[4], be8[4];
#pragma unroll
    for (int fc = 0; fc < 4; fc++) {
        int col = wc * 64 + fc * 16 + li;
        bu8[fc] = bu[col]; r8[fc] = r[col]; g8[fc] = g[col]; be8[fc] = beta[col];
    }

    float sv[2][4], s2v[2][4];
#pragma unroll
    for (int fr = 0; fr < 2; fr++)
#pragma unroll
        for (int j = 0; j < 4; j++) {
            int gr = brow + wr * 32 + fr * 16 + lo4 * 4 + j;
            float hv = 0.f;
            if (gr < M) hv = (invc[gr] > 0.f) ? 1.f : 0.f;
            float s = 0.f, s2 = 0.f;
#pragma unroll
            for (int fc = 0; fc < 4; fc++) {
                float val = acc[fr][fc][j] + bu8[fc] + hv * r8[fc];
                val = fmaxf(val, 0.f);
                acc[fr][fc][j] = val;
                s += val; s2 += val * val;
            }
#pragma unroll
            for (int m = 1; m < 16; m <<= 1) {
                s  += __shfl_xor(s, m, 64);
                s2 += __shfl_xor(s2, m, 64);
            }
            sv[fr][j] = s; s2v[fr][j] = s2;
        }

    if (li == 0) {
#pragma unroll
        for (int fr = 0; fr < 2; fr++)
#pragma unroll
            for (int j = 0; j < 4; j++) {
                int row64 = wr * 32 + fr * 16 + lo4 * 4 + j;
                ps[wc][row64]  = sv[fr][j];
                ps2[wc][row64] = s2v[fr][j];
            }
    }
    __syncthreads();

#pragma unroll
    for (int fr = 0; fr < 2; fr++)
#pragma unroll
        for (int j = 0; j < 4; j++) {
            int row64 = wr * 32 + fr * 16 + lo4 * 4 + j;
            int gr = brow + row64;
            float s  = sv[fr][j]  + ps[1 - wc][row64];
            float s2 = s2v[fr][j] + ps2[1 - wc][row64];
            float mean = s * (1.0f / 128.0f);
            float var  = s2 * (1.0f / 128.0f) - mean * mean;
            float rstd = rsqrtf(var + 1e-5f);
            if (gr < M) {
#pragma unroll
                for (int fc = 0; fc < 4; fc++) {
                    int col = wc * 64 + fc * 16 + li;
                    float o = (acc[fr][fc][j] - mean) * rstd * g8[fc] + be8[fc];
                    if (OUT_BF16) Cb[(size_t)gr * 128 + col] = f2b(o);
                    else          Cf[(size_t)gr * 128 + col] = o;
                }
            }
        }
}

// ---------------------------------------------------------------------------
extern "C" void kernel_launch(void* const* d_in, const int* in_sizes, int n_in,
                              void* d_out, int out_size, void* d_ws, size_t ws_size,
                              hipStream_t stream)
{
    const float* x    = (const float*)d_in[0];
    const int*   ei   = (const int*)d_in[1];
    const float* ea   = (const float*)d_in[2];
    const float* Wn1  = (const float*)d_in[3];
    const float* bn1  = (const float*)d_in[4];
    const float* We1  = (const float*)d_in[5];
    const float* be1  = (const float*)d_in[6];
    const float* Wu1  = (const float*)d_in[7];
    const float* bu1  = (const float*)d_in[8];
    const float* g1   = (const float*)d_in[9];
    const float* beta1= (const float*)d_in[10];
    const float* Wn2  = (const float*)d_in[11];
    const float* bn2  = (const float*)d_in[12];
    const float* We2  = (const float*)d_in[13];
    const float* be2  = (const float*)d_in[14];
    const float* Wu2  = (const float*)d_in[15];
    const float* bu2  = (const float*)d_in[16];
    const float* g2   = (const float*)d_in[17];
    const float* beta2= (const float*)d_in[18];

    const int* srcI = ei;
    const int* dstI = ei + NE;
    float* out = (float*)d_out;

    // ---- workspace layout
    float* invc = (float*)d_ws;                        // N
    int*   rp   = (int*)(invc + NN);                   // N+1
    int*   hist = rp + NN + 1;                         // N
    int*   fill = hist + NN;                           // N
    int*   psum = fill + NN;                           // 256
    int*   eperm= psum + 256;                          // E
    int*   ssrc = eperm + NE;                          // E
    uintptr_t base = ((uintptr_t)(ssrc + NE) + 15) & ~(uintptr_t)15;
    ushort* Xb    = (ushort*)base;                     // N*128 (also h1 bf16)
    ushort* meanb = Xb + (size_t)NN * 128;             // N*128
    ushort* aggEb = meanb + (size_t)NN * 128;          // N*32
    ushort* Btp1  = aggEb + (size_t)NN * 32;           // 36*128*8
    ushort* Btp2  = Btp1 + NOCT * 1024;
    float*  r1    = (float*)(Btp2 + NOCT * 1024);      // 128
    float*  r2    = r1 + 128;

    const int gemm_grid = (NN + 63) / 64;

    // ---- bf16 feature table
    castx_kernel<<<(int)(((size_t)NN * 128 / 8 + 255) / 256), 256, 0, stream>>>(x, Xb);

    // ---- CSR build (shared by both layers)
    hipMemsetAsync(hist, 0, NN * sizeof(int), stream);
    hipMemsetAsync(fill, 0, NN * sizeof(int), stream);
    hist_kernel<<<2048, 256, 0, stream>>>(dstI, hist, NE);
    scan1_kernel<<<NBLK, 256, 0, stream>>>(hist, rp, psum);
    scan2_kernel<<<1, 256, 0, stream>>>(psum);
    scan3_kernel<<<NBLK, 256, 0, stream>>>(rp, psum);
    place_kernel<<<2048, 256, 0, stream>>>(srcI, dstI, rp, fill, eperm, ssrc, NE);

    // ---- weight products (once)
    prep_kernel<<<(KTOT * 128 + 128 + 255) / 256, 256, 0, stream>>>(
        Wn1, bn1, We1, be1, Wu1, Btp1, r1);
    prep_kernel<<<(KTOT * 128 + 128 + 255) / 256, 256, 0, stream>>>(
        Wn2, bn2, We2, be2, Wu2, Btp2, r2);

    // ---- layer 1 (computes meanb + layer-invariant aggEb/invc)
    agg_kernel<true><<<(NN + 3) / 4, 256, 0, stream>>>(Xb, ea, eperm, ssrc, rp,
                                                       meanb, aggEb, invc);
    gemmF_kernel<true><<<gemm_grid, 256, 0, stream>>>(
        Xb, meanb, aggEb, invc, Btp1, r1, bu1, g1, beta1, nullptr, Xb, NN);

    // ---- layer 2 (Xb now holds h1 bf16; aggEb/invc reused)
    agg_kernel<false><<<(NN + 3) / 4, 256, 0, stream>>>(Xb, ea, eperm, ssrc, rp,
                                                        meanb, aggEb, invc);
    gemmF_kernel<false><<<gemm_grid, 256, 0, stream>>>(
        Xb, meanb, aggEb, invc, Btp2, r2, bu2, g2, beta2, out, nullptr, NN);
}